// Round 3
// baseline (113.951 us; speedup 1.0000x reference)
//
#include <hip/hip_runtime.h>
#include <hip/hip_cooperative_groups.h>
#include <math.h>

namespace cg = cooperative_groups;

#define RADIUS 5
#define DIAM   11

constexpr int TILE = 16;
constexpr int LT   = TILE + 2 * RADIUS;  // 26
constexpr int NOFF = 60;                 // positive offsets: (0,1..5), (1..5, -5..5)

// ---- compile-time spatial weight table -------------------------------------
// exp(x) for x in [-0.695, 0): Taylor to 22 terms -> exact at double precision.
constexpr double cexp_small(double x) {
    double s = 1.0, t = 1.0;
    for (int i = 1; i <= 22; ++i) { t *= x / (double)i; s += t; }
    return s;
}

struct WTab { float c1[NOFF]; float c2[NOFF]; };

constexpr WTab make_wtab() {
    WTab w{};
    for (int k = 0; k < NOFF; ++k) {
        int di, dj;
        if (k < 5) { di = 0; dj = k + 1; }
        else       { di = (k - 5) / DIAM + 1; dj = (k - 5) % DIAM - RADIUS; }
        double e = cexp_small(-(double)(di * di + dj * dj) / 72.0);
        w.c1[k] = (float)(0.9 * e);   // 0.9 * exp(-(di^2+dj^2)/72)
        w.c2[k] = (float)(0.1 * e);   // 0.1 * exp(-(di^2+dj^2)/72)
    }
    return w;
}

constexpr WTab WT = make_wtab();

// Binarize per reference: NaN -> 0, <1 -> 0, else keep value
__device__ __forceinline__ float binarize(float v) {
    return (isnan(v) || v < 1.0f) ? 0.0f : v;
}

// Pair-symmetric formulation:
//   numerator = sum over unordered pairs {p,q=p+t}, t positive offset, of
//       w(p,q) * (1 - sim(p,q)) * (ms_q*md_p + ms_p*md_q)
//   w = exp(-(di^2+dj^2)/72) * (0.9*exp(-50*|x_q-x_p|^2) + 0.1)
//   1 - sim = a + b - 2ab   (a=sig_q, b=sig_p)
//   denominator = sum of binarized md
//
// Round-3: single cooperative kernel. Rounds 0 vs 2 were identical to 3 ns
// with different inner loops -> compute (~3 us warm) is NOT the bottleneck;
// the 2-dispatch structure is. grid.sync() + block-0 finalize removes one
// dispatch boundary. Compute body is the round-2 proven version.
__global__ __launch_bounds__(256) void crf_fused(
    const float* __restrict__ x,      // [N,3,H,W]
    const float* __restrict__ y,      // [N,H,W]
    const float* __restrict__ msrc,   // [N,1,H,W]
    const float* __restrict__ mdst,   // [N,1,H,W]
    float2* __restrict__ partial,     // [gridX*gridY*N]
    float* __restrict__ out,          // [1]
    int H, int W)
{
    __shared__ float4 sP[LT][LT];   // x0,x1,x2,sigmoid(y)
    __shared__ float2 sM[LT][LT];   // binarized ms, binarized md
    __shared__ float  wRedA[4], wRedB[4];

    const int n   = blockIdx.z;
    const int ti0 = blockIdx.y * TILE;
    const int tj0 = blockIdx.x * TILE;
    const int tid = threadIdx.y * TILE + threadIdx.x;

    const long long planeHW = (long long)H * W;
    const float* xn  = x    + (long long)n * 3 * planeHW;
    const float* yn  = y    + (long long)n * planeHW;
    const float* msn = msrc + (long long)n * planeHW;
    const float* mdn = mdst + (long long)n * planeHW;

    // cooperative halo load: 676 elems / 256 threads = 3 predicated rounds.
    // All global loads unconditional (clamped addresses) so the compiler can
    // issue all 18 up front; OOB lanes select zero before the LDS write.
    #pragma unroll
    for (int it = 0; it < 3; ++it) {
        const int idx  = tid + it * 256;
        const bool act = (idx < LT * LT);
        const int cidx = act ? idx : (LT * LT - 1);
        const int li = cidx / LT, lj = cidx % LT;
        const int gi = ti0 - RADIUS + li;
        const int gj = tj0 - RADIUS + lj;
        const bool inb = (gi >= 0) && (gi < H) && (gj >= 0) && (gj < W);
        const int cg2 = min(max(gi, 0), H - 1) * W + min(max(gj, 0), W - 1);
        // 6 unconditional loads (latency overlapped across rounds)
        const float v0 = xn[cg2];
        const float v1 = xn[planeHW + cg2];
        const float v2 = xn[2 * planeHW + cg2];
        const float yv = yn[cg2];
        const float m0 = msn[cg2];
        const float m1 = mdn[cg2];
        float4 P = make_float4(0.f, 0.f, 0.f, 0.f);
        float2 M = make_float2(0.f, 0.f);
        if (inb) {
            P = make_float4(v0, v1, v2, 1.0f / (1.0f + __expf(-yv)));
            M = make_float2(binarize(m0), binarize(m1));
        }
        if (act) { sP[li][lj] = P; sM[li][lj] = M; }
    }
    __syncthreads();

    const int ci = threadIdx.y + RADIUS, cj = threadIdx.x + RADIUS;
    const int gi = ti0 + threadIdx.y,    gj = tj0 + threadIdx.x;
    const bool valid = (gi < H && gj < W);

    float lsum = 0.0f, mdb = 0.0f;
    if (valid) {
        const float4 C  = sP[ci][cj];
        const float2 Mc = sM[ci][cj];
        const float  sc   = C.w;
        const float  c1m2 = 1.0f - 2.0f * sc;   // (1-sim) = fma(a, 1-2b, b)
        mdb = Mc.y;

        float lsum0 = 0.0f, lsum1 = 0.0f;       // split dependency chain
        #pragma unroll
        for (int k = 0; k < NOFF; ++k) {
            int di, dj;   // constant-folded under full unroll
            if (k < 5) { di = 0; dj = k + 1; }
            else       { di = (k - 5) / DIAM + 1; dj = (k - 5) % DIAM - RADIUS; }
            const float4 P = sP[ci + di][cj + dj];
            const float2 M = sM[ci + di][cj + dj];
            float d0 = P.x - C.x, d1 = P.y - C.y, d2 = P.z - C.z;
            float u  = fmaf(d2, d2, fmaf(d1, d1, d0 * d0));
            float e  = __expf(-50.0f * u);
            float w  = fmaf(WT.c1[k], e, WT.c2[k]);    // literal weights, no LDS
            float oms = fmaf(P.w, c1m2, sc);           // 1 - sim
            float pm  = fmaf(Mc.x, M.y, M.x * Mc.y);   // ms_c*md_q + ms_q*md_c
            if (k & 1) lsum1 = fmaf(w * oms, pm, lsum1);
            else       lsum0 = fmaf(w * oms, pm, lsum0);
        }
        lsum = lsum0 + lsum1;
    }

    // block reduction: wave shuffle then 4 partials in LDS
    float a = lsum, b = mdb;
    #pragma unroll
    for (int off = 32; off > 0; off >>= 1) {
        a += __shfl_down(a, off, 64);
        b += __shfl_down(b, off, 64);
    }
    const int wave = tid >> 6, lane = tid & 63;
    if (lane == 0) { wRedA[wave] = a; wRedB[wave] = b; }
    __syncthreads();
    const int bid = (blockIdx.z * gridDim.y + blockIdx.y) * gridDim.x + blockIdx.x;
    if (tid == 0) {
        float t1 = wRedA[0] + wRedA[1] + wRedA[2] + wRedA[3];
        float t2 = wRedB[0] + wRedB[1] + wRedB[2] + wRedB[3];
        partial[bid] = make_float2(t1, t2);   // plain store: no init needed
    }

    // ---- grid-wide barrier, then block 0 finalizes -------------------------
    cg::this_grid().sync();

    if (bid == 0) {
        const int G = gridDim.x * gridDim.y * gridDim.z;
        float fa = 0.f, fb = 0.f;
        for (int i = tid; i < G; i += 256) {
            float2 p = partial[i];
            fa += p.x; fb += p.y;
        }
        #pragma unroll
        for (int off = 32; off > 0; off >>= 1) {
            fa += __shfl_down(fa, off, 64);
            fb += __shfl_down(fb, off, 64);
        }
        if (lane == 0) { wRedA[wave] = fa; wRedB[wave] = fb; }
        __syncthreads();
        if (tid == 0) {
            double num   = (double)wRedA[0] + wRedA[1] + wRedA[2] + wRedA[3];
            double denom = (double)wRedB[0] + wRedB[1] + wRedB[2] + wRedB[3];
            if (denom < 1.0) denom = 1.0;
            out[0] = (float)(num / denom);
        }
    }
}

extern "C" void kernel_launch(void* const* d_in, const int* in_sizes, int n_in,
                              void* d_out, int out_size, void* d_ws, size_t ws_size,
                              hipStream_t stream) {
    const float* x  = (const float*)d_in[0];
    const float* yv = (const float*)d_in[1];
    const float* ms = (const float*)d_in[2];
    const float* md = (const float*)d_in[3];
    float* out      = (float*)d_out;
    float2* partial = (float2*)d_ws;

    int H = 256, W = 256;
    const int N = in_sizes[1] / (H * W);  // y is [N,H,W]

    dim3 block(TILE, TILE);
    dim3 grid((W + TILE - 1) / TILE, (H + TILE - 1) / TILE, N);
    // 512 blocks x 256 thr = 2 blocks/CU (16.4 KB LDS) -> co-resident, safe
    // for cooperative launch.

    void* args[] = {
        (void*)&x, (void*)&yv, (void*)&ms, (void*)&md,
        (void*)&partial, (void*)&out, (void*)&H, (void*)&W
    };
    hipLaunchCooperativeKernel(reinterpret_cast<void*>(crf_fused),
                               grid, block, args, 0, stream);
}

// Round 4
// 76.535 us; speedup vs baseline: 1.4889x; 1.4889x over previous
//
#include <hip/hip_runtime.h>
#include <math.h>

#define RADIUS 5
#define DIAM   11

constexpr int TILE = 16;
constexpr int LT   = TILE + 2 * RADIUS;  // 26
constexpr int NOFF = 60;                 // positive offsets: (0,1..5), (1..5, -5..5)

// ---- compile-time spatial weight table -------------------------------------
// exp(x) for x in [-0.695, 0): Taylor to 22 terms -> exact at double precision.
constexpr double cexp_small(double x) {
    double s = 1.0, t = 1.0;
    for (int i = 1; i <= 22; ++i) { t *= x / (double)i; s += t; }
    return s;
}

struct WTab { float c1[NOFF]; float c2[NOFF]; };

constexpr WTab make_wtab() {
    WTab w{};
    for (int k = 0; k < NOFF; ++k) {
        int di, dj;
        if (k < 5) { di = 0; dj = k + 1; }
        else       { di = (k - 5) / DIAM + 1; dj = (k - 5) % DIAM - RADIUS; }
        double e = cexp_small(-(double)(di * di + dj * dj) / 72.0);
        w.c1[k] = (float)(0.9 * e);   // 0.9 * exp(-(di^2+dj^2)/72)
        w.c2[k] = (float)(0.1 * e);   // 0.1 * exp(-(di^2+dj^2)/72)
    }
    return w;
}

constexpr WTab WT = make_wtab();

// Module-scope ticket counter: lives in module .data, NOT in the poisoned
// workspace. Self-reset by the finalizing block each run -> graph-replay safe.
__device__ int g_ticket = 0;

// Binarize per reference: NaN -> 0, <1 -> 0, else keep value
__device__ __forceinline__ float binarize(float v) {
    return (isnan(v) || v < 1.0f) ? 0.0f : v;
}

// Pair-symmetric formulation:
//   numerator = sum over unordered pairs {p,q=p+t}, t positive offset, of
//       w(p,q) * (1 - sim(p,q)) * (ms_q*md_p + ms_p*md_q)
//   w = exp(-(di^2+dj^2)/72) * (0.9*exp(-50*|x_q-x_p|^2) + 0.1)
//   1 - sim = a + b - 2ab   (a=sig_q, b=sig_p)
//   denominator = sum of binarized md
//
// Round-4: single NORMAL dispatch (coop launch regressed +45 us in r3).
// Last-block-done pattern: every block stores its float2 partial, bumps a
// module-scope ticket (threadfence for cross-XCD visibility), and the block
// that draws ticket G-1 reduces all partials in crf_final's exact order
// (bit-identical result), then resets the ticket for the next graph replay.
__global__ __launch_bounds__(256) void crf_fused(
    const float* __restrict__ x,      // [N,3,H,W]
    const float* __restrict__ y,      // [N,H,W]
    const float* __restrict__ msrc,   // [N,1,H,W]
    const float* __restrict__ mdst,   // [N,1,H,W]
    float2* __restrict__ partial,     // [gridX*gridY*N]
    float* __restrict__ out,          // [1]
    int H, int W)
{
    __shared__ float4 sP[LT][LT];   // x0,x1,x2,sigmoid(y)
    __shared__ float2 sM[LT][LT];   // binarized ms, binarized md
    __shared__ float  wRedA[4], wRedB[4];
    __shared__ int    sIsLast;

    const int n   = blockIdx.z;
    const int ti0 = blockIdx.y * TILE;
    const int tj0 = blockIdx.x * TILE;
    const int tid = threadIdx.y * TILE + threadIdx.x;

    const long long planeHW = (long long)H * W;
    const float* xn  = x    + (long long)n * 3 * planeHW;
    const float* yn  = y    + (long long)n * planeHW;
    const float* msn = msrc + (long long)n * planeHW;
    const float* mdn = mdst + (long long)n * planeHW;

    // cooperative halo load: 676 elems / 256 threads = 3 predicated rounds.
    // All global loads unconditional (clamped addresses) so the compiler can
    // issue all 18 up front; OOB lanes select zero before the LDS write.
    #pragma unroll
    for (int it = 0; it < 3; ++it) {
        const int idx  = tid + it * 256;
        const bool act = (idx < LT * LT);
        const int cidx = act ? idx : (LT * LT - 1);
        const int li = cidx / LT, lj = cidx % LT;
        const int gi = ti0 - RADIUS + li;
        const int gj = tj0 - RADIUS + lj;
        const bool inb = (gi >= 0) && (gi < H) && (gj >= 0) && (gj < W);
        const int cg2 = min(max(gi, 0), H - 1) * W + min(max(gj, 0), W - 1);
        // 6 unconditional loads (latency overlapped across rounds)
        const float v0 = xn[cg2];
        const float v1 = xn[planeHW + cg2];
        const float v2 = xn[2 * planeHW + cg2];
        const float yv = yn[cg2];
        const float m0 = msn[cg2];
        const float m1 = mdn[cg2];
        float4 P = make_float4(0.f, 0.f, 0.f, 0.f);
        float2 M = make_float2(0.f, 0.f);
        if (inb) {
            P = make_float4(v0, v1, v2, 1.0f / (1.0f + __expf(-yv)));
            M = make_float2(binarize(m0), binarize(m1));
        }
        if (act) { sP[li][lj] = P; sM[li][lj] = M; }
    }
    __syncthreads();

    const int ci = threadIdx.y + RADIUS, cj = threadIdx.x + RADIUS;
    const int gi = ti0 + threadIdx.y,    gj = tj0 + threadIdx.x;
    const bool valid = (gi < H && gj < W);

    float lsum = 0.0f, mdb = 0.0f;
    if (valid) {
        const float4 C  = sP[ci][cj];
        const float2 Mc = sM[ci][cj];
        const float  sc   = C.w;
        const float  c1m2 = 1.0f - 2.0f * sc;   // (1-sim) = fma(a, 1-2b, b)
        mdb = Mc.y;

        float lsum0 = 0.0f, lsum1 = 0.0f;       // split dependency chain
        #pragma unroll
        for (int k = 0; k < NOFF; ++k) {
            int di, dj;   // constant-folded under full unroll
            if (k < 5) { di = 0; dj = k + 1; }
            else       { di = (k - 5) / DIAM + 1; dj = (k - 5) % DIAM - RADIUS; }
            const float4 P = sP[ci + di][cj + dj];
            const float2 M = sM[ci + di][cj + dj];
            float d0 = P.x - C.x, d1 = P.y - C.y, d2 = P.z - C.z;
            float u  = fmaf(d2, d2, fmaf(d1, d1, d0 * d0));
            float e  = __expf(-50.0f * u);
            float w  = fmaf(WT.c1[k], e, WT.c2[k]);    // literal weights, no LDS
            float oms = fmaf(P.w, c1m2, sc);           // 1 - sim
            float pm  = fmaf(Mc.x, M.y, M.x * Mc.y);   // ms_c*md_q + ms_q*md_c
            if (k & 1) lsum1 = fmaf(w * oms, pm, lsum1);
            else       lsum0 = fmaf(w * oms, pm, lsum0);
        }
        lsum = lsum0 + lsum1;
    }

    // block reduction: wave shuffle then 4 partials in LDS
    float a = lsum, b = mdb;
    #pragma unroll
    for (int off = 32; off > 0; off >>= 1) {
        a += __shfl_down(a, off, 64);
        b += __shfl_down(b, off, 64);
    }
    const int wave = tid >> 6, lane = tid & 63;
    if (lane == 0) { wRedA[wave] = a; wRedB[wave] = b; }
    __syncthreads();

    const int bid = (blockIdx.z * gridDim.y + blockIdx.y) * gridDim.x + blockIdx.x;
    const int G   = gridDim.x * gridDim.y * gridDim.z;

    if (tid == 0) {
        float t1 = wRedA[0] + wRedA[1] + wRedA[2] + wRedA[3];
        float t2 = wRedB[0] + wRedB[1] + wRedB[2] + wRedB[3];
        partial[bid] = make_float2(t1, t2);
        __threadfence();                       // publish partial[] device-wide
        int ticket = atomicAdd(&g_ticket, 1);  // device-scope by default
        sIsLast = (ticket == G - 1) ? 1 : 0;
    }
    __syncthreads();

    if (sIsLast) {
        __threadfence();   // acquire: all partial[] stores now visible
        // Reduce in crf_final's exact deterministic order -> bit-identical.
        float fa = 0.f, fb = 0.f;
        for (int i = tid; i < G; i += 256) {
            float2 p = partial[i];
            fa += p.x; fb += p.y;
        }
        #pragma unroll
        for (int off = 32; off > 0; off >>= 1) {
            fa += __shfl_down(fa, off, 64);
            fb += __shfl_down(fb, off, 64);
        }
        __syncthreads();   // wRedA/B reuse: prior values consumed above
        if (lane == 0) { wRedA[wave] = fa; wRedB[wave] = fb; }
        __syncthreads();
        if (tid == 0) {
            double num   = (double)wRedA[0] + wRedA[1] + wRedA[2] + wRedA[3];
            double denom = (double)wRedB[0] + wRedB[1] + wRedB[2] + wRedB[3];
            if (denom < 1.0) denom = 1.0;
            out[0] = (float)(num / denom);
            g_ticket = 0;          // reset for next graph replay
            __threadfence();
        }
    }
}

extern "C" void kernel_launch(void* const* d_in, const int* in_sizes, int n_in,
                              void* d_out, int out_size, void* d_ws, size_t ws_size,
                              hipStream_t stream) {
    const float* x  = (const float*)d_in[0];
    const float* yv = (const float*)d_in[1];
    const float* ms = (const float*)d_in[2];
    const float* md = (const float*)d_in[3];
    float* out      = (float*)d_out;
    float2* partial = (float2*)d_ws;

    const int H = 256, W = 256;
    const int N = in_sizes[1] / (H * W);  // y is [N,H,W]

    dim3 block(TILE, TILE);
    dim3 grid((W + TILE - 1) / TILE, (H + TILE - 1) / TILE, N);

    hipLaunchKernelGGL(crf_fused, grid, block, 0, stream,
                       x, yv, ms, md, partial, out, H, W);
}